// Round 5
// baseline (1447.580 us; speedup 1.0000x reference)
//
#include <hip/hip_runtime.h>

#define N_NODES 50000
#define N_EDGES 800000
#define HDIM 128
#define N_GRAPH 2048

typedef __bf16 bf16x8 __attribute__((ext_vector_type(8)));
typedef float f32x4 __attribute__((ext_vector_type(4)));

// round-to-nearest-even fp32 -> bf16
static __device__ __forceinline__ unsigned short f2bf(float f) {
    unsigned int u = __float_as_uint(f);
    u += 0x7fffu + ((u >> 16) & 1u);
    return (unsigned short)(u >> 16);
}
static __device__ __forceinline__ float bflo(unsigned int u) { return __uint_as_float(u << 16); }
static __device__ __forceinline__ float bfhi(unsigned int u) { return __uint_as_float(u & 0xFFFF0000u); }
static __device__ __forceinline__ float bf2f(unsigned short v) { return __uint_as_float((unsigned int)v << 16); }

static __device__ __forceinline__ float silu_f(float x) {
    return x / (1.0f + __expf(-x));
}

// ---- fused one-shot prep (blocks < 1408) + src histogram (blocks >= 1408) ----
#define PREP_BLOCKS 1408
#define HIST_BLOCKS 3125
__global__ void prep_hist_kernel(const float* __restrict__ ew1, const float* __restrict__ ew2,
                                 const float* __restrict__ nw1, const float* __restrict__ nw2,
                                 const float* __restrict__ eb1, const float* __restrict__ lattices,
                                 const int* __restrict__ eidx,
                                 unsigned short* __restrict__ W1aT, unsigned short* __restrict__ W1bT,
                                 unsigned short* __restrict__ W2t, unsigned short* __restrict__ N1t,
                                 unsigned short* __restrict__ N2t, unsigned short* __restrict__ Lb,
                                 int* __restrict__ buf) {
    const int bid = blockIdx.x;
    if (bid >= PREP_BLOCKS) {
        int e = (bid - PREP_BLOCKS) * 256 + threadIdx.x;
        if (e < N_EDGES) atomicAdd(&buf[eidx[e]], 1);
        return;
    }
    int i = bid * 256 + threadIdx.x;
    if (i < 16384) {
        int n = i >> 7, k = i & 127;
        W1aT[i] = f2bf(ew1[k * 128 + n]);
    } else if (i < 32768) {
        int j = i - 16384; int n = j >> 7, k = j & 127;
        W1bT[j] = f2bf(ew1[(128 + k) * 128 + n]);
    } else if (i < 49152) {
        int j = i - 32768; int n = j >> 7, k = j & 127;
        W2t[j] = f2bf(ew2[k * 128 + n]);
    } else if (i < 81920) {
        int j = i - 49152; int n = j >> 8, k = j & 255;
        N1t[j] = f2bf(nw1[k * 128 + n]);
    } else if (i < 98304) {
        int j = i - 81920; int n = j >> 7, k = j & 127;
        N2t[j] = f2bf(nw2[k * 128 + n]);
    } else if (i < 98304 + 262144) {
        int j = i - 98304; int g = j >> 7, c = j & 127;
        float s = eb1[c];
#pragma unroll
        for (int t = 0; t < 6; ++t) s += lattices[g * 6 + t] * ew1[(256 + t) * 128 + c];
        Lb[j] = f2bf(s);
    }
}

// single-block scan, LDS-chunked so all global traffic is coalesced
__global__ __launch_bounds__(1024) void scan_kernel(int* __restrict__ buf) {
    constexpr int CH = 12288;
    __shared__ int lds[CH];
    __shared__ int part[1024];
    __shared__ int carry_s;
    const int t = threadIdx.x;
    if (t == 0) carry_s = 0;
    __syncthreads();
#pragma unroll 1
    for (int base = 0; base < N_NODES; base += CH) {
#pragma unroll
        for (int k = 0; k < CH / 1024; ++k) {
            int f = k * 1024 + t;
            lds[f] = (base + f < N_NODES) ? buf[base + f] : 0;
        }
        __syncthreads();
        int loc[12];
        int s = 0;
#pragma unroll
        for (int i = 0; i < 12; ++i) { loc[i] = lds[t * 12 + i]; s += loc[i]; }
        part[t] = s;
        __syncthreads();
        for (int off = 1; off < 1024; off <<= 1) {
            int tmp = (t >= off) ? part[t - off] : 0;
            __syncthreads();
            part[t] += tmp;
            __syncthreads();
        }
        const int total = part[1023];
        int run = carry_s + part[t] - s;
#pragma unroll
        for (int i = 0; i < 12; ++i) { int tmp = loc[i]; lds[t * 12 + i] = run; run += tmp; }
        __syncthreads();
#pragma unroll
        for (int k = 0; k < CH / 1024; ++k) {
            int f = k * 1024 + t;
            if (base + f < N_NODES) buf[base + f] = lds[f];
        }
        __syncthreads();
        if (t == 0) carry_s += total;
        __syncthreads();
    }
}

// ---- fused perm scatter (blocks < 3125) + pq precompute (blocks >= 3125) ----
#define PERM_BLOCKS2 3125
#define PQ_BLOCKS ((N_NODES + 63) / 64)
__global__ __launch_bounds__(256, 4) void perm_pq_kernel(
    const int* __restrict__ eidx, int* __restrict__ buf,
    unsigned short* __restrict__ perm_lo, unsigned char* __restrict__ perm_hi,
    const float* __restrict__ nf, const unsigned short* __restrict__ W1aT,
    const unsigned short* __restrict__ W1bT,
    unsigned short* __restrict__ P, unsigned short* __restrict__ Qm) {
    constexpr int SA = 136;
    __shared__ unsigned short sm[64 * SA];
    const int bid = blockIdx.x;
    const int tid = threadIdx.x;

    if (bid < PERM_BLOCKS2) {
        int e = bid * 256 + tid;
        if (e < N_EDGES) {
            int pos = atomicAdd(&buf[eidx[e]], 1);
            perm_lo[pos] = (unsigned short)(e & 0xFFFF);
            perm_hi[pos] = (unsigned char)(e >> 16);
        }
        return;
    }

    const int n0 = (bid - PERM_BLOCKS2) * 64;
    const int mrow = tid >> 2, q = tid & 3;
    {
        const int node = n0 + mrow;
        unsigned short* row = sm + mrow * SA + q * 32;
        if (node < N_NODES) {
            const float4* a4 = (const float4*)(nf + (size_t)node * HDIM) + q * 8;
#pragma unroll
            for (int j = 0; j < 8; ++j) {
                float4 v = a4[j];
                *(ushort4*)(row + 4 * j) = make_ushort4(f2bf(v.x), f2bf(v.y), f2bf(v.z), f2bf(v.w));
            }
        } else {
#pragma unroll
            for (int j = 0; j < 8; ++j) *(ushort4*)(row + 4 * j) = make_ushort4(0, 0, 0, 0);
        }
    }
    __syncthreads();

    const int wave = tid >> 6, lane = tid & 63;
    const int lr = lane & 15, kq = lane >> 4;
    f32x4 acca[8] = {}, accb[8] = {};
    const int arow = (wave * 16 + lr) * SA;
#pragma unroll
    for (int ks = 0; ks < 128; ks += 32) {
        bf16x8 a = *(const bf16x8*)(sm + arow + ks + kq * 8);
#pragma unroll
        for (int nt = 0; nt < 8; ++nt) {
            bf16x8 ba = *(const bf16x8*)(W1aT + (nt * 16 + lr) * 128 + ks + kq * 8);
            acca[nt] = __builtin_amdgcn_mfma_f32_16x16x32_bf16(a, ba, acca[nt], 0, 0, 0);
            bf16x8 bb = *(const bf16x8*)(W1bT + (nt * 16 + lr) * 128 + ks + kq * 8);
            accb[nt] = __builtin_amdgcn_mfma_f32_16x16x32_bf16(a, bb, accb[nt], 0, 0, 0);
        }
    }
    __syncthreads();

    const int node = n0 + mrow;
#pragma unroll
    for (int nt = 0; nt < 8; ++nt) {
        const int col = nt * 16 + lr;
#pragma unroll
        for (int r = 0; r < 4; ++r)
            sm[(wave * 16 + kq * 4 + r) * SA + col] = f2bf(acca[nt][r]);
    }
    __syncthreads();
    if (node < N_NODES) {
        uint4* dst = (uint4*)(P + (size_t)node * HDIM + q * 32);
        const uint4* srcp = (const uint4*)(sm + mrow * SA + q * 32);
#pragma unroll
        for (int j = 0; j < 4; ++j) dst[j] = srcp[j];
    }
    __syncthreads();
#pragma unroll
    for (int nt = 0; nt < 8; ++nt) {
        const int col = nt * 16 + lr;
#pragma unroll
        for (int r = 0; r < 4; ++r)
            sm[(wave * 16 + kq * 4 + r) * SA + col] = f2bf(accb[nt][r]);
    }
    __syncthreads();
    if (node < N_NODES) {
        uint4* dst = (uint4*)(Qm + (size_t)node * HDIM + q * 32);
        const uint4* srcp = (const uint4*)(sm + mrow * SA + q * 32);
#pragma unroll
        for (int j = 0; j < 4; ++j) dst[j] = srcp[j];
    }
}

// ---- edge: wave-private pipeline. Each wave owns 32 sorted edges (2 tiles of 16).
// A-fragments built directly in registers (lane lr = edge, cols kq*8+j+32s),
// MFMA layer2, C staged to LDS bf16, ONE barrier, register-walk seg-reduce.
__global__ __launch_bounds__(256, 4) void edge_kernel(
    const unsigned short* __restrict__ P, const unsigned short* __restrict__ Qm,
    const unsigned short* __restrict__ Lb, const float* __restrict__ frac_diff,
    const int* __restrict__ eidx, const int* __restrict__ e2g,
    const unsigned short* __restrict__ perm_lo, const unsigned char* __restrict__ perm_hi,
    const float* __restrict__ e_w1, const unsigned short* __restrict__ W2t,
    const float* __restrict__ b2, float* __restrict__ agg) {
    constexpr int SS = 132;                     // bf16 stage row stride
    __shared__ unsigned short stg[128 * SS];    // 33792 B
    __shared__ int ssrc[128];

    const int tid = threadIdx.x;
    const int wv = tid >> 6, lane = tid & 63;
    const int lr = lane & 15, kq = lane >> 4;
    const int base = blockIdx.x * 128 + wv * 32;   // this wave's 32 edges

    // metadata for both tiles (per-lane, parallel across all waves; x4 redundant -> L1 broadcast)
    int src[2], dst[2], gg[2];
    float fd0[2], fd1[2], fd2[2];
#pragma unroll
    for (int t = 0; t < 2; ++t) {
        const int i = base + t * 16 + lr;
        const int e = (int)perm_lo[i] | ((int)perm_hi[i] << 16);
        src[t] = eidx[e];
        dst[t] = eidx[N_EDGES + e];
        gg[t] = e2g[e];
        fd0[t] = frac_diff[3 * e];
        fd1[t] = frac_diff[3 * e + 1];
        fd2[t] = frac_diff[3 * e + 2];
        if (kq == 0) ssrc[wv * 32 + t * 16 + lr] = src[t];
    }

    const float* wrbase = e_w1 + 262 * HDIM;

#pragma unroll 1
    for (int t = 0; t < 2; ++t) {
        // build A-fragments in registers: lane (lr,kq) = edge lr, cols ks*32+kq*8+j
        bf16x8 afrag[4];
#pragma unroll
        for (int ks = 0; ks < 4; ++ks) {
            const int c0 = ks * 32 + kq * 8;
            uint4 pu = *(const uint4*)(P + (size_t)src[t] * HDIM + c0);
            uint4 qu = *(const uint4*)(Qm + (size_t)dst[t] * HDIM + c0);
            uint4 lu = *(const uint4*)(Lb + (size_t)gg[t] * HDIM + c0);
            float w0[8], w1[8], w2[8];
            *(float4*)(w0) = *(const float4*)(wrbase + c0);
            *(float4*)(w0 + 4) = *(const float4*)(wrbase + c0 + 4);
            *(float4*)(w1) = *(const float4*)(wrbase + 128 + c0);
            *(float4*)(w1 + 4) = *(const float4*)(wrbase + 128 + c0 + 4);
            *(float4*)(w2) = *(const float4*)(wrbase + 256 + c0);
            *(float4*)(w2 + 4) = *(const float4*)(wrbase + 256 + c0 + 4);
            const unsigned int* pw = (const unsigned int*)&pu;
            const unsigned int* qw = (const unsigned int*)&qu;
            const unsigned int* lw = (const unsigned int*)&lu;
            unsigned int ow[4];
#pragma unroll
            for (int w = 0; w < 4; ++w) {
                float x0 = bflo(pw[w]) + bflo(qw[w]) + bflo(lw[w])
                         + fd0[t] * w0[2 * w] + fd1[t] * w1[2 * w] + fd2[t] * w2[2 * w];
                float x1 = bfhi(pw[w]) + bfhi(qw[w]) + bfhi(lw[w])
                         + fd0[t] * w0[2 * w + 1] + fd1[t] * w1[2 * w + 1] + fd2[t] * w2[2 * w + 1];
                ow[w] = (unsigned int)f2bf(silu_f(x0)) | ((unsigned int)f2bf(silu_f(x1)) << 16);
            }
            afrag[ks] = *(bf16x8*)ow;
        }

        // layer 2 MFMA (K=128)
        f32x4 acc[8] = {};
#pragma unroll
        for (int ks = 0; ks < 4; ++ks) {
#pragma unroll
            for (int nt = 0; nt < 8; ++nt) {
                bf16x8 bb = *(const bf16x8*)(W2t + (nt * 16 + lr) * 128 + ks * 32 + kq * 8);
                acc[nt] = __builtin_amdgcn_mfma_f32_16x16x32_bf16(afrag[ks], bb, acc[nt], 0, 0, 0);
            }
        }

        // stage silu(acc+bias) bf16 into this wave's LDS region
#pragma unroll
        for (int nt = 0; nt < 8; ++nt) {
            const int col = nt * 16 + lr;
            const float bias = b2[col];
#pragma unroll
            for (int r = 0; r < 4; ++r) {
                const int row = wv * 32 + t * 16 + kq * 4 + r;
                stg[row * SS + col] = f2bf(silu_f(acc[nt][r] + bias));
            }
        }
    }
    __syncthreads();

    // segmented reduction over this wave's 32 sorted rows; wave-uniform branches
    int s_[32];
#pragma unroll
    for (int r = 0; r < 32; ++r) s_[r] = ssrc[wv * 32 + r];   // broadcast reads
#pragma unroll 1
    for (int p = 0; p < 2; ++p) {
        const int col = lane + 64 * p;
        float v[32];
#pragma unroll
        for (int r = 0; r < 32; ++r) v[r] = bf2f(stg[(wv * 32 + r) * SS + col]);
        float sum = 0.0f;
#pragma unroll
        for (int r = 0; r < 32; ++r) {
            sum += v[r];
            const bool bnd = (r == 31) ? true : (s_[r + (r < 31 ? 1 : 0)] != s_[r]);
            if (bnd) {
                atomicAdd(&agg[(size_t)s_[r] * HDIM + col], sum);
                sum = 0.0f;
            }
        }
    }
}

// ---- node MLP: h = concat(nf, agg/cnt) -> silu -> silu -> + nf (agg aliases out) ----
__global__ __launch_bounds__(256, 4) void node_kernel(
    const float* __restrict__ nf, const float* __restrict__ agg,
    const int* __restrict__ buf,
    const unsigned short* __restrict__ N1t, const float* __restrict__ b1,
    const unsigned short* __restrict__ N2t, const float* __restrict__ b2,
    float* __restrict__ out) {
    constexpr int SA = 264;
    constexpr int S2 = 136;
    constexpr int SFo = 132;
    __shared__ unsigned short sm[64 * SA];
    float* smf = (float*)sm;

    const int tid = threadIdx.x;
    const int n0 = blockIdx.x * 64;
    const int mrow = tid >> 2, q = tid & 3;
    {
        const int node = n0 + mrow;
        unsigned short* row = sm + mrow * SA;
        const int cbq = q * 32;
        if (node < N_NODES) {
            const int c = buf[node] - (node ? buf[node - 1] : 0);
            const float inv = 1.0f / (float)max(c, 1);
            const float4* a4 = (const float4*)(nf + (size_t)node * HDIM) + q * 8;
            const float4* g4 = (const float4*)(agg + (size_t)node * HDIM) + q * 8;
#pragma unroll
            for (int j = 0; j < 8; ++j) {
                float4 v = a4[j];
                *(ushort4*)(row + cbq + 4 * j) =
                    make_ushort4(f2bf(v.x), f2bf(v.y), f2bf(v.z), f2bf(v.w));
                float4 g = g4[j];
                *(ushort4*)(row + HDIM + cbq + 4 * j) =
                    make_ushort4(f2bf(g.x * inv), f2bf(g.y * inv), f2bf(g.z * inv), f2bf(g.w * inv));
            }
        } else {
#pragma unroll
            for (int j = 0; j < 8; ++j) {
                *(ushort4*)(row + cbq + 4 * j) = make_ushort4(0, 0, 0, 0);
                *(ushort4*)(row + HDIM + cbq + 4 * j) = make_ushort4(0, 0, 0, 0);
            }
        }
    }
    __syncthreads();

    const int wave = tid >> 6, lane = tid & 63;
    const int lr = lane & 15, kq = lane >> 4;

    f32x4 acc[8] = {};
    const int arow = (wave * 16 + lr) * SA;
#pragma unroll
    for (int ks = 0; ks < 256; ks += 32) {
        bf16x8 a = *(const bf16x8*)(sm + arow + ks + kq * 8);
#pragma unroll
        for (int nt = 0; nt < 8; ++nt) {
            bf16x8 bb = *(const bf16x8*)(N1t + (nt * 16 + lr) * 256 + ks + kq * 8);
            acc[nt] = __builtin_amdgcn_mfma_f32_16x16x32_bf16(a, bb, acc[nt], 0, 0, 0);
        }
    }
    __syncthreads();

#pragma unroll
    for (int nt = 0; nt < 8; ++nt) {
        const int col = nt * 16 + lr;
        const float bias = b1[col];
#pragma unroll
        for (int r = 0; r < 4; ++r) {
            const int mm = wave * 16 + kq * 4 + r;
            sm[mm * S2 + col] = f2bf(silu_f(acc[nt][r] + bias));
        }
    }
    __syncthreads();

    f32x4 acc2[8] = {};
    const int arow2 = (wave * 16 + lr) * S2;
#pragma unroll
    for (int ks = 0; ks < 128; ks += 32) {
        bf16x8 a = *(const bf16x8*)(sm + arow2 + ks + kq * 8);
#pragma unroll
        for (int nt = 0; nt < 8; ++nt) {
            bf16x8 bb = *(const bf16x8*)(N2t + (nt * 16 + lr) * 128 + ks + kq * 8);
            acc2[nt] = __builtin_amdgcn_mfma_f32_16x16x32_bf16(a, bb, acc2[nt], 0, 0, 0);
        }
    }
    __syncthreads();

#pragma unroll
    for (int nt = 0; nt < 8; ++nt) {
        const int col = nt * 16 + lr;
        const float bias = b2[col];
#pragma unroll
        for (int r = 0; r < 4; ++r) {
            const int mm = wave * 16 + kq * 4 + r;
            smf[mm * SFo + col] = silu_f(acc2[nt][r] + bias);
        }
    }
    __syncthreads();
    {
        const int node = n0 + mrow;
        if (node < N_NODES) {
            const float4* nfr = (const float4*)(nf + (size_t)node * HDIM) + q * 8;
            float4* outr = (float4*)(out + (size_t)node * HDIM) + q * 8;
            const float* st = smf + mrow * SFo + q * 32;
#pragma unroll
            for (int j = 0; j < 8; ++j) {
                float4 v = nfr[j];
                float4 s4 = *(const float4*)(st + 4 * j);
                v.x += s4.x; v.y += s4.y; v.z += s4.z; v.w += s4.w;
                outr[j] = v;
            }
        }
    }
}

extern "C" void kernel_launch(void* const* d_in, const int* in_sizes, int n_in,
                              void* d_out, int out_size, void* d_ws, size_t ws_size,
                              hipStream_t stream) {
    const float* node_features = (const float*)d_in[0];
    const float* lattices = (const float*)d_in[2];
    const float* frac_diff = (const float*)d_in[3];
    const int* edge_index = (const int*)d_in[4];
    const int* edge2graph = (const int*)d_in[5];
    const float* e_w1 = (const float*)d_in[6];
    const float* e_b1 = (const float*)d_in[7];
    const float* e_w2 = (const float*)d_in[8];
    const float* e_b2 = (const float*)d_in[9];
    const float* n_w1 = (const float*)d_in[10];
    const float* n_b1 = (const float*)d_in[11];
    const float* n_w2 = (const float*)d_in[12];
    const float* n_b2 = (const float*)d_in[13];

    // workspace layout (bytes), total 28,920,896 (R3-proven size):
    //   0         W1aT | 32768 W1bT | 65536 W2t | 98304 N1t | 163840 N2t
    //   196608    Lb   (G*128 bf16)
    //   720896    P    (N*128 bf16, 12.8MB)
    //   13520896  Q    (N*128 bf16, 12.8MB)
    //   26320896  buf  (N int: hist -> offsets -> inclusive prefix)
    //   26520896  perm_lo (E u16) | 28120896 perm_hi (E u8)
    // agg lives in d_out (node_kernel reads its own rows before overwriting).
    char* ws = (char*)d_ws;
    unsigned short* W1aT = (unsigned short*)(ws);
    unsigned short* W1bT = (unsigned short*)(ws + 32768);
    unsigned short* W2t  = (unsigned short*)(ws + 65536);
    unsigned short* N1t  = (unsigned short*)(ws + 98304);
    unsigned short* N2t  = (unsigned short*)(ws + 163840);
    unsigned short* Lb   = (unsigned short*)(ws + 196608);
    unsigned short* P    = (unsigned short*)(ws + 720896);
    unsigned short* Qm   = (unsigned short*)(ws + 13520896);
    int* buf             = (int*)(ws + 26320896);
    unsigned short* perm_lo = (unsigned short*)(ws + 26520896);
    unsigned char* perm_hi  = (unsigned char*)(ws + 28120896);
    float* agg = (float*)d_out;

    hipMemsetAsync(d_out, 0, (size_t)N_NODES * HDIM * 4, stream);
    hipMemsetAsync(buf, 0, (size_t)N_NODES * 4, stream);

    prep_hist_kernel<<<PREP_BLOCKS + HIST_BLOCKS, 256, 0, stream>>>(
        e_w1, e_w2, n_w1, n_w2, e_b1, lattices, edge_index,
        W1aT, W1bT, W2t, N1t, N2t, Lb, buf);

    scan_kernel<<<1, 1024, 0, stream>>>(buf);

    perm_pq_kernel<<<PERM_BLOCKS2 + PQ_BLOCKS, 256, 0, stream>>>(
        edge_index, buf, perm_lo, perm_hi, node_features, W1aT, W1bT, P, Qm);

    edge_kernel<<<N_EDGES / 128, 256, 0, stream>>>(
        P, Qm, Lb, frac_diff, edge_index, edge2graph, perm_lo, perm_hi,
        e_w1, W2t, e_b2, agg);

    node_kernel<<<(N_NODES + 63) / 64, 256, 0, stream>>>(
        node_features, agg, buf, N1t, n_b1, N2t, n_b2, (float*)d_out);
}

// Round 6
// 628.362 us; speedup vs baseline: 2.3037x; 2.3037x over previous
//
#include <hip/hip_runtime.h>

#define N_NODES 50000
#define N_EDGES 800000
#define HDIM 128
#define N_GRAPH 2048

typedef __bf16 bf16x8 __attribute__((ext_vector_type(8)));
typedef float f32x4 __attribute__((ext_vector_type(4)));

// round-to-nearest-even fp32 -> bf16
static __device__ __forceinline__ unsigned short f2bf(float f) {
    unsigned int u = __float_as_uint(f);
    u += 0x7fffu + ((u >> 16) & 1u);
    return (unsigned short)(u >> 16);
}
static __device__ __forceinline__ float bflo(unsigned int u) { return __uint_as_float(u << 16); }
static __device__ __forceinline__ float bfhi(unsigned int u) { return __uint_as_float(u & 0xFFFF0000u); }

static __device__ __forceinline__ float silu_f(float x) {
    return x / (1.0f + __expf(-x));
}

// ---- fused one-shot prep (blocks < 1408) + src histogram (blocks >= 1408) ----
#define PREP_BLOCKS 1408
#define HIST_BLOCKS 3125
__global__ void prep_hist_kernel(const float* __restrict__ ew1, const float* __restrict__ ew2,
                                 const float* __restrict__ nw1, const float* __restrict__ nw2,
                                 const float* __restrict__ eb1, const float* __restrict__ lattices,
                                 const int* __restrict__ eidx,
                                 unsigned short* __restrict__ W1aT, unsigned short* __restrict__ W1bT,
                                 unsigned short* __restrict__ W2t, unsigned short* __restrict__ N1t,
                                 unsigned short* __restrict__ N2t, unsigned short* __restrict__ Lb,
                                 int* __restrict__ buf) {
    const int bid = blockIdx.x;
    if (bid >= PREP_BLOCKS) {
        int e = (bid - PREP_BLOCKS) * 256 + threadIdx.x;
        if (e < N_EDGES) atomicAdd(&buf[eidx[e]], 1);
        return;
    }
    int i = bid * 256 + threadIdx.x;
    if (i < 16384) {
        int n = i >> 7, k = i & 127;
        W1aT[i] = f2bf(ew1[k * 128 + n]);
    } else if (i < 32768) {
        int j = i - 16384; int n = j >> 7, k = j & 127;
        W1bT[j] = f2bf(ew1[(128 + k) * 128 + n]);
    } else if (i < 49152) {
        int j = i - 32768; int n = j >> 7, k = j & 127;
        W2t[j] = f2bf(ew2[k * 128 + n]);
    } else if (i < 81920) {
        int j = i - 49152; int n = j >> 8, k = j & 255;
        N1t[j] = f2bf(nw1[k * 128 + n]);
    } else if (i < 98304) {
        int j = i - 81920; int n = j >> 7, k = j & 127;
        N2t[j] = f2bf(nw2[k * 128 + n]);
    } else if (i < 98304 + 262144) {
        int j = i - 98304; int g = j >> 7, c = j & 127;
        float s = eb1[c];
#pragma unroll
        for (int t = 0; t < 6; ++t) s += lattices[g * 6 + t] * ew1[(256 + t) * 128 + c];
        Lb[j] = f2bf(s);
    }
}

// single-block scan, LDS-chunked so all global traffic is coalesced
__global__ __launch_bounds__(1024) void scan_kernel(int* __restrict__ buf) {
    constexpr int CH = 12288;
    __shared__ int lds[CH];
    __shared__ int part[1024];
    __shared__ int carry_s;
    const int t = threadIdx.x;
    if (t == 0) carry_s = 0;
    __syncthreads();
#pragma unroll 1
    for (int base = 0; base < N_NODES; base += CH) {
#pragma unroll
        for (int k = 0; k < CH / 1024; ++k) {
            int f = k * 1024 + t;
            lds[f] = (base + f < N_NODES) ? buf[base + f] : 0;
        }
        __syncthreads();
        int loc[12];
        int s = 0;
#pragma unroll
        for (int i = 0; i < 12; ++i) { loc[i] = lds[t * 12 + i]; s += loc[i]; }
        part[t] = s;
        __syncthreads();
        for (int off = 1; off < 1024; off <<= 1) {
            int tmp = (t >= off) ? part[t - off] : 0;
            __syncthreads();
            part[t] += tmp;
            __syncthreads();
        }
        const int total = part[1023];
        int run = carry_s + part[t] - s;
#pragma unroll
        for (int i = 0; i < 12; ++i) { int tmp = loc[i]; lds[t * 12 + i] = run; run += tmp; }
        __syncthreads();
#pragma unroll
        for (int k = 0; k < CH / 1024; ++k) {
            int f = k * 1024 + t;
            if (base + f < N_NODES) buf[base + f] = lds[f];
        }
        __syncthreads();
        if (t == 0) carry_s += total;
        __syncthreads();
    }
}

// ---- fused perm scatter (blocks < 3125) + pq precompute (blocks >= 3125) ----
#define PERM_BLOCKS2 3125
#define PQ_BLOCKS ((N_NODES + 63) / 64)
__global__ __launch_bounds__(256, 4) void perm_pq_kernel(
    const int* __restrict__ eidx, int* __restrict__ buf,
    unsigned short* __restrict__ perm_lo, unsigned char* __restrict__ perm_hi,
    const float* __restrict__ nf, const unsigned short* __restrict__ W1aT,
    const unsigned short* __restrict__ W1bT,
    unsigned short* __restrict__ P, unsigned short* __restrict__ Qm) {
    constexpr int SA = 136;
    __shared__ unsigned short sm[64 * SA];
    const int bid = blockIdx.x;
    const int tid = threadIdx.x;

    if (bid < PERM_BLOCKS2) {
        int e = bid * 256 + tid;
        if (e < N_EDGES) {
            int pos = atomicAdd(&buf[eidx[e]], 1);
            perm_lo[pos] = (unsigned short)(e & 0xFFFF);
            perm_hi[pos] = (unsigned char)(e >> 16);
        }
        return;
    }

    const int n0 = (bid - PERM_BLOCKS2) * 64;
    const int mrow = tid >> 2, q = tid & 3;
    {
        const int node = n0 + mrow;
        unsigned short* row = sm + mrow * SA + q * 32;
        if (node < N_NODES) {
            const float4* a4 = (const float4*)(nf + (size_t)node * HDIM) + q * 8;
#pragma unroll
            for (int j = 0; j < 8; ++j) {
                float4 v = a4[j];
                *(ushort4*)(row + 4 * j) = make_ushort4(f2bf(v.x), f2bf(v.y), f2bf(v.z), f2bf(v.w));
            }
        } else {
#pragma unroll
            for (int j = 0; j < 8; ++j) *(ushort4*)(row + 4 * j) = make_ushort4(0, 0, 0, 0);
        }
    }
    __syncthreads();

    const int wave = tid >> 6, lane = tid & 63;
    const int lr = lane & 15, kq = lane >> 4;
    f32x4 acca[8] = {}, accb[8] = {};
    const int arow = (wave * 16 + lr) * SA;
#pragma unroll
    for (int ks = 0; ks < 128; ks += 32) {
        bf16x8 a = *(const bf16x8*)(sm + arow + ks + kq * 8);
#pragma unroll
        for (int nt = 0; nt < 8; ++nt) {
            bf16x8 ba = *(const bf16x8*)(W1aT + (nt * 16 + lr) * 128 + ks + kq * 8);
            acca[nt] = __builtin_amdgcn_mfma_f32_16x16x32_bf16(a, ba, acca[nt], 0, 0, 0);
            bf16x8 bb = *(const bf16x8*)(W1bT + (nt * 16 + lr) * 128 + ks + kq * 8);
            accb[nt] = __builtin_amdgcn_mfma_f32_16x16x32_bf16(a, bb, accb[nt], 0, 0, 0);
        }
    }
    __syncthreads();

    const int node = n0 + mrow;
#pragma unroll
    for (int nt = 0; nt < 8; ++nt) {
        const int col = nt * 16 + lr;
#pragma unroll
        for (int r = 0; r < 4; ++r)
            sm[(wave * 16 + kq * 4 + r) * SA + col] = f2bf(acca[nt][r]);
    }
    __syncthreads();
    if (node < N_NODES) {
        uint4* dst = (uint4*)(P + (size_t)node * HDIM + q * 32);
        const uint4* srcp = (const uint4*)(sm + mrow * SA + q * 32);
#pragma unroll
        for (int j = 0; j < 4; ++j) dst[j] = srcp[j];
    }
    __syncthreads();
#pragma unroll
    for (int nt = 0; nt < 8; ++nt) {
        const int col = nt * 16 + lr;
#pragma unroll
        for (int r = 0; r < 4; ++r)
            sm[(wave * 16 + kq * 4 + r) * SA + col] = f2bf(accb[nt][r]);
    }
    __syncthreads();
    if (node < N_NODES) {
        uint4* dst = (uint4*)(Qm + (size_t)node * HDIM + q * 32);
        const uint4* srcp = (const uint4*)(sm + mrow * SA + q * 32);
#pragma unroll
        for (int j = 0; j < 4; ++j) dst[j] = srcp[j];
    }
}

// ---- edge kernel: wave-private, ZERO LDS, ZERO barriers.
// Each wave owns 16 sorted edges: lane (lr,kq) = edge lr, k-chunk kq.
// A-fragments built in registers; layer-2 MFMA; segmented reduction done
// on the C-fragment layout via shuffle prefix sums:
//   seg[a,b] emitted as +prefix[b] to src[b] and -prefix[a-1] to src[a]
// (one pair of atomics per boundary row -> ~19M atomics total, no spills).
__global__ __launch_bounds__(256, 2) void edge_kernel(
    const unsigned short* __restrict__ P, const unsigned short* __restrict__ Qm,
    const unsigned short* __restrict__ Lb, const float* __restrict__ frac_diff,
    const int* __restrict__ eidx, const int* __restrict__ e2g,
    const unsigned short* __restrict__ perm_lo, const unsigned char* __restrict__ perm_hi,
    const float* __restrict__ e_w1, const unsigned short* __restrict__ W2t,
    const float* __restrict__ b2, float* __restrict__ agg) {
    const int tid = threadIdx.x;
    const int wv = tid >> 6, lane = tid & 63;
    const int lr = lane & 15, kq = lane >> 4;
    const int base = blockIdx.x * 64 + wv * 16;   // this wave's 16 edges

    // per-lane metadata for edge lr (x4 redundant across kq; L1 broadcast)
    const int i = base + lr;
    const int e = (int)perm_lo[i] | ((int)perm_hi[i] << 16);
    const int src = eidx[e];
    const int dst = eidx[N_EDGES + e];
    const int g = e2g[e];
    const float fd0 = frac_diff[3 * e];
    const float fd1 = frac_diff[3 * e + 1];
    const float fd2 = frac_diff[3 * e + 2];

    // src ids for this lane's C rows (kq*4+r) and their successors, via shuffle
    int sc[4], sn[4];
#pragma unroll
    for (int r = 0; r < 4; ++r) {
        const int row = kq * 4 + r;
        sc[r] = __shfl(src, row);
        sn[r] = __shfl(src, (row + 1) & 15);   // row 15: wraps, masked below
    }

    // build A-fragments in registers: afrag[ks] = e1 cols ks*32+kq*8 .. +8
    const float* wrbase = e_w1 + 262 * HDIM;
    bf16x8 afrag[4];
#pragma unroll
    for (int ks = 0; ks < 4; ++ks) {
        const int c0 = ks * 32 + kq * 8;
        uint4 pu = *(const uint4*)(P + (size_t)src * HDIM + c0);
        uint4 qu = *(const uint4*)(Qm + (size_t)dst * HDIM + c0);
        uint4 lu = *(const uint4*)(Lb + (size_t)g * HDIM + c0);
        float w0[8], w1[8], w2[8];
        *(float4*)(w0) = *(const float4*)(wrbase + c0);
        *(float4*)(w0 + 4) = *(const float4*)(wrbase + c0 + 4);
        *(float4*)(w1) = *(const float4*)(wrbase + 128 + c0);
        *(float4*)(w1 + 4) = *(const float4*)(wrbase + 128 + c0 + 4);
        *(float4*)(w2) = *(const float4*)(wrbase + 256 + c0);
        *(float4*)(w2 + 4) = *(const float4*)(wrbase + 256 + c0 + 4);
        const unsigned int* pw = (const unsigned int*)&pu;
        const unsigned int* qw = (const unsigned int*)&qu;
        const unsigned int* lw = (const unsigned int*)&lu;
        unsigned int ow[4];
#pragma unroll
        for (int w = 0; w < 4; ++w) {
            float x0 = bflo(pw[w]) + bflo(qw[w]) + bflo(lw[w])
                     + fd0 * w0[2 * w] + fd1 * w1[2 * w] + fd2 * w2[2 * w];
            float x1 = bfhi(pw[w]) + bfhi(qw[w]) + bfhi(lw[w])
                     + fd0 * w0[2 * w + 1] + fd1 * w1[2 * w + 1] + fd2 * w2[2 * w + 1];
            ow[w] = (unsigned int)f2bf(silu_f(x0)) | ((unsigned int)f2bf(silu_f(x1)) << 16);
        }
        afrag[ks] = *(bf16x8*)ow;
    }

    // layer-2 MFMA (K=128), all 8 col-tiles
    f32x4 acc[8] = {};
#pragma unroll
    for (int ks = 0; ks < 4; ++ks) {
#pragma unroll
        for (int nt = 0; nt < 8; ++nt) {
            bf16x8 bb = *(const bf16x8*)(W2t + (nt * 16 + lr) * 128 + ks * 32 + kq * 8);
            acc[nt] = __builtin_amdgcn_mfma_f32_16x16x32_bf16(afrag[ks], bb, acc[nt], 0, 0, 0);
        }
    }

    // shuffle-based segmented reduction on C layout (no LDS, no arrays)
#pragma unroll
    for (int nt = 0; nt < 8; ++nt) {
        const int col = nt * 16 + lr;
        const float bias = b2[col];
        float p0 = silu_f(acc[nt][0] + bias);
        float p1 = p0 + silu_f(acc[nt][1] + bias);
        float p2 = p1 + silu_f(acc[nt][2] + bias);
        float p3 = p2 + silu_f(acc[nt][3] + bias);
        // group totals from lower kq groups
        float t1 = __shfl_up(p3, 16);
        float t2 = __shfl_up(p3, 32);
        float t3 = __shfl_up(p3, 48);
        float off = 0.0f;
        if (kq > 0) off += t1;
        if (kq > 1) off += t2;
        if (kq > 2) off += t3;
        float pr[4] = { p0 + off, p1 + off, p2 + off, p3 + off };
#pragma unroll
        for (int r = 0; r < 4; ++r) {
            const int row = kq * 4 + r;
            const bool last = (row == 15);
            const bool bnd = last || (sc[r] != sn[r]);
            if (bnd) {
                atomicAdd(&agg[(size_t)sc[r] * HDIM + col], pr[r]);
                if (!last) atomicAdd(&agg[(size_t)sn[r] * HDIM + col], -pr[r]);
            }
        }
    }
}

// ---- node MLP: h = concat(nf, agg/cnt) -> silu -> silu -> + nf (agg aliases out) ----
__global__ __launch_bounds__(256, 4) void node_kernel(
    const float* __restrict__ nf, const float* __restrict__ agg,
    const int* __restrict__ buf,
    const unsigned short* __restrict__ N1t, const float* __restrict__ b1,
    const unsigned short* __restrict__ N2t, const float* __restrict__ b2,
    float* __restrict__ out) {
    constexpr int SA = 264;
    constexpr int S2 = 136;
    constexpr int SFo = 132;
    __shared__ unsigned short sm[64 * SA];
    float* smf = (float*)sm;

    const int tid = threadIdx.x;
    const int n0 = blockIdx.x * 64;
    const int mrow = tid >> 2, q = tid & 3;
    {
        const int node = n0 + mrow;
        unsigned short* row = sm + mrow * SA;
        const int cbq = q * 32;
        if (node < N_NODES) {
            const int c = buf[node] - (node ? buf[node - 1] : 0);
            const float inv = 1.0f / (float)max(c, 1);
            const float4* a4 = (const float4*)(nf + (size_t)node * HDIM) + q * 8;
            const float4* g4 = (const float4*)(agg + (size_t)node * HDIM) + q * 8;
#pragma unroll
            for (int j = 0; j < 8; ++j) {
                float4 v = a4[j];
                *(ushort4*)(row + cbq + 4 * j) =
                    make_ushort4(f2bf(v.x), f2bf(v.y), f2bf(v.z), f2bf(v.w));
                float4 g = g4[j];
                *(ushort4*)(row + HDIM + cbq + 4 * j) =
                    make_ushort4(f2bf(g.x * inv), f2bf(g.y * inv), f2bf(g.z * inv), f2bf(g.w * inv));
            }
        } else {
#pragma unroll
            for (int j = 0; j < 8; ++j) {
                *(ushort4*)(row + cbq + 4 * j) = make_ushort4(0, 0, 0, 0);
                *(ushort4*)(row + HDIM + cbq + 4 * j) = make_ushort4(0, 0, 0, 0);
            }
        }
    }
    __syncthreads();

    const int wave = tid >> 6, lane = tid & 63;
    const int lr = lane & 15, kq = lane >> 4;

    f32x4 acc[8] = {};
    const int arow = (wave * 16 + lr) * SA;
#pragma unroll
    for (int ks = 0; ks < 256; ks += 32) {
        bf16x8 a = *(const bf16x8*)(sm + arow + ks + kq * 8);
#pragma unroll
        for (int nt = 0; nt < 8; ++nt) {
            bf16x8 bb = *(const bf16x8*)(N1t + (nt * 16 + lr) * 256 + ks + kq * 8);
            acc[nt] = __builtin_amdgcn_mfma_f32_16x16x32_bf16(a, bb, acc[nt], 0, 0, 0);
        }
    }
    __syncthreads();

#pragma unroll
    for (int nt = 0; nt < 8; ++nt) {
        const int col = nt * 16 + lr;
        const float bias = b1[col];
#pragma unroll
        for (int r = 0; r < 4; ++r) {
            const int mm = wave * 16 + kq * 4 + r;
            sm[mm * S2 + col] = f2bf(silu_f(acc[nt][r] + bias));
        }
    }
    __syncthreads();

    f32x4 acc2[8] = {};
    const int arow2 = (wave * 16 + lr) * S2;
#pragma unroll
    for (int ks = 0; ks < 128; ks += 32) {
        bf16x8 a = *(const bf16x8*)(sm + arow2 + ks + kq * 8);
#pragma unroll
        for (int nt = 0; nt < 8; ++nt) {
            bf16x8 bb = *(const bf16x8*)(N2t + (nt * 16 + lr) * 128 + ks + kq * 8);
            acc2[nt] = __builtin_amdgcn_mfma_f32_16x16x32_bf16(a, bb, acc2[nt], 0, 0, 0);
        }
    }
    __syncthreads();

#pragma unroll
    for (int nt = 0; nt < 8; ++nt) {
        const int col = nt * 16 + lr;
        const float bias = b2[col];
#pragma unroll
        for (int r = 0; r < 4; ++r) {
            const int mm = wave * 16 + kq * 4 + r;
            smf[mm * SFo + col] = silu_f(acc2[nt][r] + bias);
        }
    }
    __syncthreads();
    {
        const int node = n0 + mrow;
        if (node < N_NODES) {
            const float4* nfr = (const float4*)(nf + (size_t)node * HDIM) + q * 8;
            float4* outr = (float4*)(out + (size_t)node * HDIM) + q * 8;
            const float* st = smf + mrow * SFo + q * 32;
#pragma unroll
            for (int j = 0; j < 8; ++j) {
                float4 v = nfr[j];
                float4 s4 = *(const float4*)(st + 4 * j);
                v.x += s4.x; v.y += s4.y; v.z += s4.z; v.w += s4.w;
                outr[j] = v;
            }
        }
    }
}

extern "C" void kernel_launch(void* const* d_in, const int* in_sizes, int n_in,
                              void* d_out, int out_size, void* d_ws, size_t ws_size,
                              hipStream_t stream) {
    const float* node_features = (const float*)d_in[0];
    const float* lattices = (const float*)d_in[2];
    const float* frac_diff = (const float*)d_in[3];
    const int* edge_index = (const int*)d_in[4];
    const int* edge2graph = (const int*)d_in[5];
    const float* e_w1 = (const float*)d_in[6];
    const float* e_b1 = (const float*)d_in[7];
    const float* e_w2 = (const float*)d_in[8];
    const float* e_b2 = (const float*)d_in[9];
    const float* n_w1 = (const float*)d_in[10];
    const float* n_b1 = (const float*)d_in[11];
    const float* n_w2 = (const float*)d_in[12];
    const float* n_b2 = (const float*)d_in[13];

    // workspace layout (bytes), total 28,920,896 (R3-proven size):
    //   0         W1aT | 32768 W1bT | 65536 W2t | 98304 N1t | 163840 N2t
    //   196608    Lb   (G*128 bf16)
    //   720896    P    (N*128 bf16, 12.8MB)
    //   13520896  Q    (N*128 bf16, 12.8MB)
    //   26320896  buf  (N int: hist -> offsets -> inclusive prefix)
    //   26520896  perm_lo (E u16) | 28120896 perm_hi (E u8)
    // agg lives in d_out (node_kernel reads its own rows before overwriting).
    char* ws = (char*)d_ws;
    unsigned short* W1aT = (unsigned short*)(ws);
    unsigned short* W1bT = (unsigned short*)(ws + 32768);
    unsigned short* W2t  = (unsigned short*)(ws + 65536);
    unsigned short* N1t  = (unsigned short*)(ws + 98304);
    unsigned short* N2t  = (unsigned short*)(ws + 163840);
    unsigned short* Lb   = (unsigned short*)(ws + 196608);
    unsigned short* P    = (unsigned short*)(ws + 720896);
    unsigned short* Qm   = (unsigned short*)(ws + 13520896);
    int* buf             = (int*)(ws + 26320896);
    unsigned short* perm_lo = (unsigned short*)(ws + 26520896);
    unsigned char* perm_hi  = (unsigned char*)(ws + 28120896);
    float* agg = (float*)d_out;

    hipMemsetAsync(d_out, 0, (size_t)N_NODES * HDIM * 4, stream);
    hipMemsetAsync(buf, 0, (size_t)N_NODES * 4, stream);

    prep_hist_kernel<<<PREP_BLOCKS + HIST_BLOCKS, 256, 0, stream>>>(
        e_w1, e_w2, n_w1, n_w2, e_b1, lattices, edge_index,
        W1aT, W1bT, W2t, N1t, N2t, Lb, buf);

    scan_kernel<<<1, 1024, 0, stream>>>(buf);

    perm_pq_kernel<<<PERM_BLOCKS2 + PQ_BLOCKS, 256, 0, stream>>>(
        edge_index, buf, perm_lo, perm_hi, node_features, W1aT, W1bT, P, Qm);

    edge_kernel<<<N_EDGES / 64, 256, 0, stream>>>(
        P, Qm, Lb, frac_diff, edge_index, edge2graph, perm_lo, perm_hi,
        e_w1, W2t, e_b2, agg);

    node_kernel<<<(N_NODES + 63) / 64, 256, 0, stream>>>(
        node_features, agg, buf, N1t, n_b1, N2t, n_b2, (float*)d_out);
}

// Round 7
// 589.590 us; speedup vs baseline: 2.4552x; 1.0658x over previous
//
#include <hip/hip_runtime.h>

#define N_NODES 50000
#define N_EDGES 800000
#define HDIM 128
#define N_GRAPH 2048

typedef __bf16 bf16x8 __attribute__((ext_vector_type(8)));
typedef float f32x4 __attribute__((ext_vector_type(4)));

// round-to-nearest-even fp32 -> bf16
static __device__ __forceinline__ unsigned short f2bf(float f) {
    unsigned int u = __float_as_uint(f);
    u += 0x7fffu + ((u >> 16) & 1u);
    return (unsigned short)(u >> 16);
}
static __device__ __forceinline__ float bflo(unsigned int u) { return __uint_as_float(u << 16); }
static __device__ __forceinline__ float bfhi(unsigned int u) { return __uint_as_float(u & 0xFFFF0000u); }

// fast silu: x * rcp(1 + 2^(-x*log2e)) -> v_exp_f32 + v_rcp_f32, ~5 inst
// (vs ~25 for precise OCML exp + precise fdiv). rel err ~1e-5 << bf16 rounding.
static __device__ __forceinline__ float silu_f(float x) {
    float e = __builtin_amdgcn_exp2f(x * -1.44269504f);
    return x * __builtin_amdgcn_rcpf(1.0f + e);
}

// ---- fused one-shot prep (blocks < 1408) + src histogram (blocks >= 1408) ----
#define PREP_BLOCKS 1408
#define HIST_BLOCKS 3125
__global__ void prep_hist_kernel(const float* __restrict__ ew1, const float* __restrict__ ew2,
                                 const float* __restrict__ nw1, const float* __restrict__ nw2,
                                 const float* __restrict__ eb1, const float* __restrict__ lattices,
                                 const int* __restrict__ eidx,
                                 unsigned short* __restrict__ W1aT, unsigned short* __restrict__ W1bT,
                                 unsigned short* __restrict__ W2t, unsigned short* __restrict__ N1t,
                                 unsigned short* __restrict__ N2t, unsigned short* __restrict__ Lb,
                                 int* __restrict__ buf) {
    const int bid = blockIdx.x;
    if (bid >= PREP_BLOCKS) {
        int e = (bid - PREP_BLOCKS) * 256 + threadIdx.x;
        if (e < N_EDGES) atomicAdd(&buf[eidx[e]], 1);
        return;
    }
    int i = bid * 256 + threadIdx.x;
    if (i < 16384) {
        int n = i >> 7, k = i & 127;
        W1aT[i] = f2bf(ew1[k * 128 + n]);
    } else if (i < 32768) {
        int j = i - 16384; int n = j >> 7, k = j & 127;
        W1bT[j] = f2bf(ew1[(128 + k) * 128 + n]);
    } else if (i < 49152) {
        int j = i - 32768; int n = j >> 7, k = j & 127;
        W2t[j] = f2bf(ew2[k * 128 + n]);
    } else if (i < 81920) {
        int j = i - 49152; int n = j >> 8, k = j & 255;
        N1t[j] = f2bf(nw1[k * 128 + n]);
    } else if (i < 98304) {
        int j = i - 81920; int n = j >> 7, k = j & 127;
        N2t[j] = f2bf(nw2[k * 128 + n]);
    } else if (i < 98304 + 262144) {
        int j = i - 98304; int g = j >> 7, c = j & 127;
        float s = eb1[c];
#pragma unroll
        for (int t = 0; t < 6; ++t) s += lattices[g * 6 + t] * ew1[(256 + t) * 128 + c];
        Lb[j] = f2bf(s);
    }
}

// single-block scan, LDS-chunked so all global traffic is coalesced
__global__ __launch_bounds__(1024) void scan_kernel(int* __restrict__ buf) {
    constexpr int CH = 12288;
    __shared__ int lds[CH];
    __shared__ int part[1024];
    __shared__ int carry_s;
    const int t = threadIdx.x;
    if (t == 0) carry_s = 0;
    __syncthreads();
#pragma unroll 1
    for (int base = 0; base < N_NODES; base += CH) {
#pragma unroll
        for (int k = 0; k < CH / 1024; ++k) {
            int f = k * 1024 + t;
            lds[f] = (base + f < N_NODES) ? buf[base + f] : 0;
        }
        __syncthreads();
        int loc[12];
        int s = 0;
#pragma unroll
        for (int i = 0; i < 12; ++i) { loc[i] = lds[t * 12 + i]; s += loc[i]; }
        part[t] = s;
        __syncthreads();
        for (int off = 1; off < 1024; off <<= 1) {
            int tmp = (t >= off) ? part[t - off] : 0;
            __syncthreads();
            part[t] += tmp;
            __syncthreads();
        }
        const int total = part[1023];
        int run = carry_s + part[t] - s;
#pragma unroll
        for (int i = 0; i < 12; ++i) { int tmp = loc[i]; lds[t * 12 + i] = run; run += tmp; }
        __syncthreads();
#pragma unroll
        for (int k = 0; k < CH / 1024; ++k) {
            int f = k * 1024 + t;
            if (base + f < N_NODES) buf[base + f] = lds[f];
        }
        __syncthreads();
        if (t == 0) carry_s += total;
        __syncthreads();
    }
}

// ---- fused perm scatter (blocks < 3125) + pq precompute (blocks >= 3125) ----
// packed!=0: emit 16B sorted metadata record {u16 src,dst,g; bf16 fd0,fd1,fd2}
#define PERM_BLOCKS2 3125
#define PQ_BLOCKS ((N_NODES + 63) / 64)
__global__ __launch_bounds__(256, 4) void perm_pq_kernel(
    const int* __restrict__ eidx, const int* __restrict__ e2g,
    const float* __restrict__ frac_diff, int* __restrict__ buf,
    unsigned short* __restrict__ perm_lo, unsigned char* __restrict__ perm_hi,
    uint4* __restrict__ rec, const int packed,
    const float* __restrict__ nf, const unsigned short* __restrict__ W1aT,
    const unsigned short* __restrict__ W1bT,
    unsigned short* __restrict__ P, unsigned short* __restrict__ Qm) {
    constexpr int SA = 136;
    __shared__ unsigned short sm[64 * SA];
    const int bid = blockIdx.x;
    const int tid = threadIdx.x;

    if (bid < PERM_BLOCKS2) {
        int e = bid * 256 + tid;
        if (e < N_EDGES) {
            int s = eidx[e];
            int pos = atomicAdd(&buf[s], 1);
            if (packed) {
                int d = eidx[N_EDGES + e];
                int g = e2g[e];
                unsigned int w0 = (unsigned int)s | ((unsigned int)d << 16);
                unsigned int w1 = (unsigned int)g | ((unsigned int)f2bf(frac_diff[3 * e]) << 16);
                unsigned int w2 = (unsigned int)f2bf(frac_diff[3 * e + 1]) |
                                  ((unsigned int)f2bf(frac_diff[3 * e + 2]) << 16);
                rec[pos] = make_uint4(w0, w1, w2, 0u);
            } else {
                perm_lo[pos] = (unsigned short)(e & 0xFFFF);
                perm_hi[pos] = (unsigned char)(e >> 16);
            }
        }
        return;
    }

    const int n0 = (bid - PERM_BLOCKS2) * 64;
    const int mrow = tid >> 2, q = tid & 3;
    {
        const int node = n0 + mrow;
        unsigned short* row = sm + mrow * SA + q * 32;
        if (node < N_NODES) {
            const float4* a4 = (const float4*)(nf + (size_t)node * HDIM) + q * 8;
#pragma unroll
            for (int j = 0; j < 8; ++j) {
                float4 v = a4[j];
                *(ushort4*)(row + 4 * j) = make_ushort4(f2bf(v.x), f2bf(v.y), f2bf(v.z), f2bf(v.w));
            }
        } else {
#pragma unroll
            for (int j = 0; j < 8; ++j) *(ushort4*)(row + 4 * j) = make_ushort4(0, 0, 0, 0);
        }
    }
    __syncthreads();

    const int wave = tid >> 6, lane = tid & 63;
    const int lr = lane & 15, kq = lane >> 4;
    f32x4 acca[8] = {}, accb[8] = {};
    const int arow = (wave * 16 + lr) * SA;
#pragma unroll
    for (int ks = 0; ks < 128; ks += 32) {
        bf16x8 a = *(const bf16x8*)(sm + arow + ks + kq * 8);
#pragma unroll
        for (int nt = 0; nt < 8; ++nt) {
            bf16x8 ba = *(const bf16x8*)(W1aT + (nt * 16 + lr) * 128 + ks + kq * 8);
            acca[nt] = __builtin_amdgcn_mfma_f32_16x16x32_bf16(a, ba, acca[nt], 0, 0, 0);
            bf16x8 bb = *(const bf16x8*)(W1bT + (nt * 16 + lr) * 128 + ks + kq * 8);
            accb[nt] = __builtin_amdgcn_mfma_f32_16x16x32_bf16(a, bb, accb[nt], 0, 0, 0);
        }
    }
    __syncthreads();

    const int node = n0 + mrow;
#pragma unroll
    for (int nt = 0; nt < 8; ++nt) {
        const int col = nt * 16 + lr;
#pragma unroll
        for (int r = 0; r < 4; ++r)
            sm[(wave * 16 + kq * 4 + r) * SA + col] = f2bf(acca[nt][r]);
    }
    __syncthreads();
    if (node < N_NODES) {
        uint4* dst = (uint4*)(P + (size_t)node * HDIM + q * 32);
        const uint4* srcp = (const uint4*)(sm + mrow * SA + q * 32);
#pragma unroll
        for (int j = 0; j < 4; ++j) dst[j] = srcp[j];
    }
    __syncthreads();
#pragma unroll
    for (int nt = 0; nt < 8; ++nt) {
        const int col = nt * 16 + lr;
#pragma unroll
        for (int r = 0; r < 4; ++r)
            sm[(wave * 16 + kq * 4 + r) * SA + col] = f2bf(accb[nt][r]);
    }
    __syncthreads();
    if (node < N_NODES) {
        uint4* dst = (uint4*)(Qm + (size_t)node * HDIM + q * 32);
        const uint4* srcp = (const uint4*)(sm + mrow * SA + q * 32);
#pragma unroll
        for (int j = 0; j < 4; ++j) dst[j] = srcp[j];
    }
}

// ---- edge kernel: wave-private, ZERO LDS, ZERO barriers. R6 structure.
// PACKED: metadata from one coalesced 16B record instead of 7 random gathers.
template <bool PACKED>
__global__ __launch_bounds__(256, 2) void edge_kernel(
    const unsigned short* __restrict__ P, const unsigned short* __restrict__ Qm,
    const unsigned short* __restrict__ Lb, const float* __restrict__ frac_diff,
    const int* __restrict__ eidx, const int* __restrict__ e2g,
    const unsigned short* __restrict__ perm_lo, const unsigned char* __restrict__ perm_hi,
    const uint4* __restrict__ rec,
    const float* __restrict__ e_w1, const unsigned short* __restrict__ W2t,
    const float* __restrict__ b2, float* __restrict__ agg) {
    const int tid = threadIdx.x;
    const int wv = tid >> 6, lane = tid & 63;
    const int lr = lane & 15, kq = lane >> 4;
    const int base = blockIdx.x * 64 + wv * 16;   // this wave's 16 edges

    int src, dst, g;
    float fd0, fd1, fd2;
    if (PACKED) {
        const uint4 rv = rec[base + lr];
        src = rv.x & 0xFFFF;
        dst = rv.x >> 16;
        g = rv.y & 0xFFFF;
        fd0 = bfhi(rv.y);
        fd1 = bflo(rv.z);
        fd2 = bfhi(rv.z);
    } else {
        const int i = base + lr;
        const int e = (int)perm_lo[i] | ((int)perm_hi[i] << 16);
        src = eidx[e];
        dst = eidx[N_EDGES + e];
        g = e2g[e];
        fd0 = frac_diff[3 * e];
        fd1 = frac_diff[3 * e + 1];
        fd2 = frac_diff[3 * e + 2];
    }

    // src ids for this lane's C rows (kq*4+r) and successors, via shuffle
    int sc[4], sn[4];
#pragma unroll
    for (int r = 0; r < 4; ++r) {
        const int row = kq * 4 + r;
        sc[r] = __shfl(src, row);
        sn[r] = __shfl(src, (row + 1) & 15);
    }

    // build A-fragments in registers: afrag[ks] = e1 cols ks*32+kq*8 .. +8
    const float* wrbase = e_w1 + 262 * HDIM;
    bf16x8 afrag[4];
#pragma unroll
    for (int ks = 0; ks < 4; ++ks) {
        const int c0 = ks * 32 + kq * 8;
        uint4 pu = *(const uint4*)(P + (size_t)src * HDIM + c0);
        uint4 qu = *(const uint4*)(Qm + (size_t)dst * HDIM + c0);
        uint4 lu = *(const uint4*)(Lb + (size_t)g * HDIM + c0);
        float w0[8], w1[8], w2[8];
        *(float4*)(w0) = *(const float4*)(wrbase + c0);
        *(float4*)(w0 + 4) = *(const float4*)(wrbase + c0 + 4);
        *(float4*)(w1) = *(const float4*)(wrbase + 128 + c0);
        *(float4*)(w1 + 4) = *(const float4*)(wrbase + 128 + c0 + 4);
        *(float4*)(w2) = *(const float4*)(wrbase + 256 + c0);
        *(float4*)(w2 + 4) = *(const float4*)(wrbase + 256 + c0 + 4);
        const unsigned int* pw = (const unsigned int*)&pu;
        const unsigned int* qw = (const unsigned int*)&qu;
        const unsigned int* lw = (const unsigned int*)&lu;
        unsigned int ow[4];
#pragma unroll
        for (int w = 0; w < 4; ++w) {
            float x0 = bflo(pw[w]) + bflo(qw[w]) + bflo(lw[w])
                     + fd0 * w0[2 * w] + fd1 * w1[2 * w] + fd2 * w2[2 * w];
            float x1 = bfhi(pw[w]) + bfhi(qw[w]) + bfhi(lw[w])
                     + fd0 * w0[2 * w + 1] + fd1 * w1[2 * w + 1] + fd2 * w2[2 * w + 1];
            ow[w] = (unsigned int)f2bf(silu_f(x0)) | ((unsigned int)f2bf(silu_f(x1)) << 16);
        }
        afrag[ks] = *(bf16x8*)ow;
    }

    // layer-2 MFMA (K=128), all 8 col-tiles
    f32x4 acc[8] = {};
#pragma unroll
    for (int ks = 0; ks < 4; ++ks) {
#pragma unroll
        for (int nt = 0; nt < 8; ++nt) {
            bf16x8 bb = *(const bf16x8*)(W2t + (nt * 16 + lr) * 128 + ks * 32 + kq * 8);
            acc[nt] = __builtin_amdgcn_mfma_f32_16x16x32_bf16(afrag[ks], bb, acc[nt], 0, 0, 0);
        }
    }

    // shuffle-based segmented reduction on C layout:
    // seg[a,b] emitted as +prefix[b] to src[b], -prefix[a-1] to src[a]
#pragma unroll
    for (int nt = 0; nt < 8; ++nt) {
        const int col = nt * 16 + lr;
        const float bias = b2[col];
        float p0 = silu_f(acc[nt][0] + bias);
        float p1 = p0 + silu_f(acc[nt][1] + bias);
        float p2 = p1 + silu_f(acc[nt][2] + bias);
        float p3 = p2 + silu_f(acc[nt][3] + bias);
        float t1 = __shfl_up(p3, 16);
        float t2 = __shfl_up(p3, 32);
        float t3 = __shfl_up(p3, 48);
        float off = 0.0f;
        if (kq > 0) off += t1;
        if (kq > 1) off += t2;
        if (kq > 2) off += t3;
        float pr[4] = { p0 + off, p1 + off, p2 + off, p3 + off };
#pragma unroll
        for (int r = 0; r < 4; ++r) {
            const int row = kq * 4 + r;
            const bool last = (row == 15);
            const bool bnd = last || (sc[r] != sn[r]);
            if (bnd) {
                atomicAdd(&agg[(size_t)sc[r] * HDIM + col], pr[r]);
                if (!last) atomicAdd(&agg[(size_t)sn[r] * HDIM + col], -pr[r]);
            }
        }
    }
}

// ---- node MLP: h = concat(nf, agg/cnt) -> silu -> silu -> + nf (agg aliases out) ----
__global__ __launch_bounds__(256, 4) void node_kernel(
    const float* __restrict__ nf, const float* __restrict__ agg,
    const int* __restrict__ buf,
    const unsigned short* __restrict__ N1t, const float* __restrict__ b1,
    const unsigned short* __restrict__ N2t, const float* __restrict__ b2,
    float* __restrict__ out) {
    constexpr int SA = 264;
    constexpr int S2 = 136;
    constexpr int SFo = 132;
    __shared__ unsigned short sm[64 * SA];
    float* smf = (float*)sm;

    const int tid = threadIdx.x;
    const int n0 = blockIdx.x * 64;
    const int mrow = tid >> 2, q = tid & 3;
    {
        const int node = n0 + mrow;
        unsigned short* row = sm + mrow * SA;
        const int cbq = q * 32;
        if (node < N_NODES) {
            const int c = buf[node] - (node ? buf[node - 1] : 0);
            const float inv = 1.0f / (float)max(c, 1);
            const float4* a4 = (const float4*)(nf + (size_t)node * HDIM) + q * 8;
            const float4* g4 = (const float4*)(agg + (size_t)node * HDIM) + q * 8;
#pragma unroll
            for (int j = 0; j < 8; ++j) {
                float4 v = a4[j];
                *(ushort4*)(row + cbq + 4 * j) =
                    make_ushort4(f2bf(v.x), f2bf(v.y), f2bf(v.z), f2bf(v.w));
                float4 g = g4[j];
                *(ushort4*)(row + HDIM + cbq + 4 * j) =
                    make_ushort4(f2bf(g.x * inv), f2bf(g.y * inv), f2bf(g.z * inv), f2bf(g.w * inv));
            }
        } else {
#pragma unroll
            for (int j = 0; j < 8; ++j) {
                *(ushort4*)(row + cbq + 4 * j) = make_ushort4(0, 0, 0, 0);
                *(ushort4*)(row + HDIM + cbq + 4 * j) = make_ushort4(0, 0, 0, 0);
            }
        }
    }
    __syncthreads();

    const int wave = tid >> 6, lane = tid & 63;
    const int lr = lane & 15, kq = lane >> 4;

    f32x4 acc[8] = {};
    const int arow = (wave * 16 + lr) * SA;
#pragma unroll
    for (int ks = 0; ks < 256; ks += 32) {
        bf16x8 a = *(const bf16x8*)(sm + arow + ks + kq * 8);
#pragma unroll
        for (int nt = 0; nt < 8; ++nt) {
            bf16x8 bb = *(const bf16x8*)(N1t + (nt * 16 + lr) * 256 + ks + kq * 8);
            acc[nt] = __builtin_amdgcn_mfma_f32_16x16x32_bf16(a, bb, acc[nt], 0, 0, 0);
        }
    }
    __syncthreads();

#pragma unroll
    for (int nt = 0; nt < 8; ++nt) {
        const int col = nt * 16 + lr;
        const float bias = b1[col];
#pragma unroll
        for (int r = 0; r < 4; ++r) {
            const int mm = wave * 16 + kq * 4 + r;
            sm[mm * S2 + col] = f2bf(silu_f(acc[nt][r] + bias));
        }
    }
    __syncthreads();

    f32x4 acc2[8] = {};
    const int arow2 = (wave * 16 + lr) * S2;
#pragma unroll
    for (int ks = 0; ks < 128; ks += 32) {
        bf16x8 a = *(const bf16x8*)(sm + arow2 + ks + kq * 8);
#pragma unroll
        for (int nt = 0; nt < 8; ++nt) {
            bf16x8 bb = *(const bf16x8*)(N2t + (nt * 16 + lr) * 128 + ks + kq * 8);
            acc2[nt] = __builtin_amdgcn_mfma_f32_16x16x32_bf16(a, bb, acc2[nt], 0, 0, 0);
        }
    }
    __syncthreads();

#pragma unroll
    for (int nt = 0; nt < 8; ++nt) {
        const int col = nt * 16 + lr;
        const float bias = b2[col];
#pragma unroll
        for (int r = 0; r < 4; ++r) {
            const int mm = wave * 16 + kq * 4 + r;
            smf[mm * SFo + col] = silu_f(acc2[nt][r] + bias);
        }
    }
    __syncthreads();
    {
        const int node = n0 + mrow;
        if (node < N_NODES) {
            const float4* nfr = (const float4*)(nf + (size_t)node * HDIM) + q * 8;
            float4* outr = (float4*)(out + (size_t)node * HDIM) + q * 8;
            const float* st = smf + mrow * SFo + q * 32;
#pragma unroll
            for (int j = 0; j < 8; ++j) {
                float4 v = nfr[j];
                float4 s4 = *(const float4*)(st + 4 * j);
                v.x += s4.x; v.y += s4.y; v.z += s4.z; v.w += s4.w;
                outr[j] = v;
            }
        }
    }
}

extern "C" void kernel_launch(void* const* d_in, const int* in_sizes, int n_in,
                              void* d_out, int out_size, void* d_ws, size_t ws_size,
                              hipStream_t stream) {
    const float* node_features = (const float*)d_in[0];
    const float* lattices = (const float*)d_in[2];
    const float* frac_diff = (const float*)d_in[3];
    const int* edge_index = (const int*)d_in[4];
    const int* edge2graph = (const int*)d_in[5];
    const float* e_w1 = (const float*)d_in[6];
    const float* e_b1 = (const float*)d_in[7];
    const float* e_w2 = (const float*)d_in[8];
    const float* e_b2 = (const float*)d_in[9];
    const float* n_w1 = (const float*)d_in[10];
    const float* n_b1 = (const float*)d_in[11];
    const float* n_w2 = (const float*)d_in[12];
    const float* n_b2 = (const float*)d_in[13];

    // workspace layout (bytes):
    //   0         W1aT | 32768 W1bT | 65536 W2t | 98304 N1t | 163840 N2t
    //   196608    Lb   (G*128 bf16)
    //   720896    P    (N*128 bf16, 12.8MB)
    //   13520896  Q    (N*128 bf16, 12.8MB)
    //   26320896  buf  (N int)
    //   26520896  perm_lo (E u16) | 28120896 perm_hi (E u8)   [fallback path]
    //   28920896  rec  (E x 16B packed sorted metadata)       [packed path, if ws fits]
    // agg lives in d_out (node_kernel reads its own rows before overwriting).
    char* ws = (char*)d_ws;
    unsigned short* W1aT = (unsigned short*)(ws);
    unsigned short* W1bT = (unsigned short*)(ws + 32768);
    unsigned short* W2t  = (unsigned short*)(ws + 65536);
    unsigned short* N1t  = (unsigned short*)(ws + 98304);
    unsigned short* N2t  = (unsigned short*)(ws + 163840);
    unsigned short* Lb   = (unsigned short*)(ws + 196608);
    unsigned short* P    = (unsigned short*)(ws + 720896);
    unsigned short* Qm   = (unsigned short*)(ws + 13520896);
    int* buf             = (int*)(ws + 26320896);
    unsigned short* perm_lo = (unsigned short*)(ws + 26520896);
    unsigned char* perm_hi  = (unsigned char*)(ws + 28120896);
    uint4* rec           = (uint4*)(ws + 28920896);
    float* agg = (float*)d_out;

    // ws_size is fixed for the session -> this branch is deterministic (graph-safe)
    const int packed = (ws_size >= 28920896 + (size_t)N_EDGES * 16) ? 1 : 0;

    hipMemsetAsync(d_out, 0, (size_t)N_NODES * HDIM * 4, stream);
    hipMemsetAsync(buf, 0, (size_t)N_NODES * 4, stream);

    prep_hist_kernel<<<PREP_BLOCKS + HIST_BLOCKS, 256, 0, stream>>>(
        e_w1, e_w2, n_w1, n_w2, e_b1, lattices, edge_index,
        W1aT, W1bT, W2t, N1t, N2t, Lb, buf);

    scan_kernel<<<1, 1024, 0, stream>>>(buf);

    perm_pq_kernel<<<PERM_BLOCKS2 + PQ_BLOCKS, 256, 0, stream>>>(
        edge_index, edge2graph, frac_diff, buf, perm_lo, perm_hi, rec, packed,
        node_features, W1aT, W1bT, P, Qm);

    if (packed) {
        edge_kernel<true><<<N_EDGES / 64, 256, 0, stream>>>(
            P, Qm, Lb, frac_diff, edge_index, edge2graph, perm_lo, perm_hi, rec,
            e_w1, W2t, e_b2, agg);
    } else {
        edge_kernel<false><<<N_EDGES / 64, 256, 0, stream>>>(
            P, Qm, Lb, frac_diff, edge_index, edge2graph, perm_lo, perm_hi, rec,
            e_w1, W2t, e_b2, agg);
    }

    node_kernel<<<(N_NODES + 63) / 64, 256, 0, stream>>>(
        node_features, agg, buf, N1t, n_b1, N2t, n_b2, (float*)d_out);
}